// Round 18
// baseline (275.933 us; speedup 1.0000x reference)
//
#include <hip/hip_runtime.h>
#include <hip/hip_bf16.h>

#define TT 2048
#define CCH 1024
#define HH 16
#define DD 64
#define BB 4
#define MM (BB*TT)

typedef __attribute__((ext_vector_type(4))) float f32x4;
typedef __attribute__((ext_vector_type(8))) short short8;
typedef __attribute__((ext_vector_type(8))) unsigned short u16x8;
typedef __attribute__((ext_vector_type(4))) unsigned short u16x4;

__device__ __forceinline__ unsigned short f2b(float f) {
    unsigned int u = __float_as_uint(f);
    u += 0x7fffu + ((u >> 16) & 1u);
    return (unsigned short)(u >> 16);
}
// native HW convert (compiler emits v_cvt_pk_bf16_f32 for pairs)
__device__ __forceinline__ unsigned short f2b_hw(float f) {
    __hip_bfloat16 h = __float2bfloat16(f);
    return reinterpret_cast<unsigned short&>(h);
}
__device__ __forceinline__ float b2f(unsigned short u) {
    return __uint_as_float(((unsigned int)u) << 16);
}
__device__ __forceinline__ int finite_f(float v) {
    return ((__float_as_uint(v) >> 23) & 0xFFu) != 0xFFu;
}
__device__ __forceinline__ float exp2_hw(float x) {
    return __builtin_amdgcn_exp2f(x);
}

// async global->LDS, 16B per lane (dest must be wave-uniform base + lane*16)
typedef const __attribute__((address_space(1))) unsigned int g_u32;
typedef __attribute__((address_space(3))) unsigned int l_u32;
__device__ __forceinline__ void gl_lds16(const unsigned short* g, unsigned short* l) {
    __builtin_amdgcn_global_load_lds((g_u32*)g, (l_u32*)l, 16, 0, 0);
}

// ---------------- input-dtype detector ----------------
__global__ __launch_bounds__(64) void detect_k(const unsigned int* __restrict__ x,
                                               int* __restrict__ flag) {
    int tid = threadIdx.x;
    int cnt = 0;
#pragma unroll
    for (int i = 0; i < 16; ++i) {
        unsigned int w = x[tid * 16 + i];
        unsigned int lo = w & 0xFFFFu;
        unsigned int e = (lo >> 7) & 0xFFu;
        if ((e >= 0x62u && e <= 0x90u) || lo == 0u) ++cnt;
    }
#pragma unroll
    for (int o = 32; o; o >>= 1) cnt += __shfl_down(cnt, o);
    if (tid == 0) *flag = (cnt >= 640) ? 1 : 0;
}

// ---------------- cast/copy x -> bf16 ----------------
__global__ __launch_bounds__(256) void cast_x_k(const void* __restrict__ in,
                                                unsigned short* __restrict__ out,
                                                const int* __restrict__ flag) {
    int g = blockIdx.x * 256 + threadIdx.x;
    if (*flag) {
        *(u16x8*)(out + (size_t)g * 8) =
            *(const u16x8*)((const unsigned short*)in + (size_t)g * 8);
    } else {
        const float4* p = (const float4*)((const float*)in + (size_t)g * 8);
        float4 v0 = p[0], v1 = p[1];
        u16x8 o;
        o[0] = f2b(v0.x); o[1] = f2b(v0.y); o[2] = f2b(v0.z); o[3] = f2b(v0.w);
        o[4] = f2b(v1.x); o[5] = f2b(v1.y); o[6] = f2b(v1.z); o[7] = f2b(v1.w);
        *(u16x8*)(out + (size_t)g * 8) = o;
    }
}

// ------------- W transpose(+cast): [R][Cc] -> bf16 [Cc][R] -------------
__global__ __launch_bounds__(256) void wtrans_k(const void* __restrict__ in,
                                                unsigned short* __restrict__ out,
                                                int R, int Cc,
                                                const int* __restrict__ flag) {
    __shared__ float tile[32][33];
    const int tid = threadIdx.x;
    const int c0 = blockIdx.x * 32, r0 = blockIdx.y * 32;
    const int isb = *flag;
#pragma unroll
    for (int i = 0; i < 4; ++i) {
        int e = i * 256 + tid;
        int row = e >> 5, col = e & 31;
        size_t idx = (size_t)(r0 + row) * Cc + (c0 + col);
        tile[row][col] = isb ? b2f(((const unsigned short*)in)[idx])
                             : ((const float*)in)[idx];
    }
    __syncthreads();
#pragma unroll
    for (int i = 0; i < 4; ++i) {
        int e = i * 256 + tid;
        int crow = e >> 5, rcol = e & 31;
        out[(size_t)(c0 + crow) * R + (r0 + rcol)] = f2b(tile[rcol][crow]);
    }
}

// ------------- V transpose: bf16 [bh][2048][64] -> [bh][64][2048] -------------
__global__ __launch_bounds__(256) void vtrans_k(const unsigned short* __restrict__ V,
                                                unsigned short* __restrict__ VT) {
    __shared__ unsigned short tile[64][68];
    const int tid = threadIdx.x;
    const int t0 = blockIdx.x * 64;
    const int bh = blockIdx.y;
    const unsigned short* in = V + ((size_t)bh * TT + t0) * DD;
#pragma unroll
    for (int i = 0; i < 4; ++i) {
        int cid = i * 256 + tid;
        int row = cid >> 4;
        int ch  = cid & 15;
        u16x4 v = *(const u16x4*)(in + row * DD + ch * 4);
        *(u16x4*)&tile[row][ch * 4] = v;
    }
    __syncthreads();
    unsigned short* out = VT + (size_t)bh * DD * TT + t0;
#pragma unroll
    for (int i = 0; i < 4; ++i) {
        int cid = i * 256 + tid;
        int drow = cid >> 4;
        int tch  = cid & 15;
        u16x4 v;
        v[0] = tile[tch * 4 + 0][drow];
        v[1] = tile[tch * 4 + 1][drow];
        v[2] = tile[tch * 4 + 2][drow];
        v[3] = tile[tch * 4 + 3][drow];
        *(u16x4*)(out + (size_t)drow * TT + tch * 4) = v;
    }
}

// -------- QKV GEMM: xb[M][K] bf16 @ WqkvT[N][K] bf16 + bias --------
// BK=64 gl_lds staging (source-swizzled) + LDS-staged coalesced epilogue.
__global__ __launch_bounds__(256) void gemm_qkv(const unsigned short* __restrict__ A,
                                                const unsigned short* __restrict__ Bt,
                                                const void* __restrict__ bias,
                                                unsigned short* __restrict__ outQ,
                                                unsigned short* __restrict__ outK,
                                                unsigned short* __restrict__ outV,
                                                const int* __restrict__ flag) {
    __shared__ __align__(16) char smem[34816];   // As 16K | Bs 16K; epi: 4x8704
    unsigned short* As = (unsigned short*)smem;
    unsigned short* Bs = (unsigned short*)(smem + 16384);
    const int Ksz = CCH;
    const int tid = threadIdx.x;
    const int lane = tid & 63;
    const int wid = tid >> 6;
    const int bm = blockIdx.y * 128;
    const int bn = blockIdx.x * 128;
    const int wm = (wid >> 1) * 64;
    const int wn = (wid & 1) * 64;
    const int r8 = tid >> 3;            // 0..31
    const int c8 = tid & 7;             // granule slot
    const int cg = c8 ^ (r8 & 7);       // swizzled source granule
    const int l15 = lane & 15, l4 = lane >> 4;
    const int isb = *flag;

    f32x4 acc[4][4];
#pragma unroll
    for (int i = 0; i < 4; ++i)
#pragma unroll
        for (int j = 0; j < 4; ++j)
            acc[i][j] = (f32x4){0.f, 0.f, 0.f, 0.f};

    const unsigned short* pac[4];
    const unsigned short* pbc[4];
    unsigned short* lac[4];
    unsigned short* lbc[4];
#pragma unroll
    for (int ch = 0; ch < 4; ++ch) {
        pac[ch] = A  + (size_t)(bm + ch * 32 + r8) * Ksz + cg * 8;
        pbc[ch] = Bt + (size_t)(bn + ch * 32 + r8) * Ksz + cg * 8;
        lac[ch] = &As[ch * 2048 + tid * 8];   // linear dest (byte = 16*tid)
        lbc[ch] = &Bs[ch * 2048 + tid * 8];
    }

    for (int kt = 0; kt < Ksz; kt += 64) {
        __syncthreads();
#pragma unroll
        for (int ch = 0; ch < 4; ++ch) gl_lds16(pac[ch] + kt, lac[ch]);
#pragma unroll
        for (int ch = 0; ch < 4; ++ch) gl_lds16(pbc[ch] + kt, lbc[ch]);
        __syncthreads();
#pragma unroll
        for (int kk = 0; kk < 2; ++kk) {
            short8 af[4], bfr[4];
#pragma unroll
            for (int mi = 0; mi < 4; ++mi)
                af[mi] = *(const short8*)&As[(wm + mi * 16 + l15) * 64
                                             + (((l4 + kk * 4) ^ (l15 & 7)) * 8)];
#pragma unroll
            for (int ni = 0; ni < 4; ++ni)
                bfr[ni] = *(const short8*)&Bs[(wn + ni * 16 + l15) * 64
                                              + (((l4 + kk * 4) ^ (l15 & 7)) * 8)];
#pragma unroll
            for (int mi = 0; mi < 4; ++mi)
#pragma unroll
                for (int ni = 0; ni < 4; ++ni)
                    acc[mi][ni] = __builtin_amdgcn_mfma_f32_16x16x32_bf16(
                        af[mi], bfr[ni], acc[mi][ni], 0, 0, 0);
        }
    }

    // ---- coalesced epilogue via LDS (reuse staging space; As/Bs dead) ----
    __syncthreads();   // all waves done with fragment reads
    unsigned short (*Ot)[68] = (unsigned short (*)[68])(smem + wid * 8704);
    const int colb = bn + wn;                 // wave's 64-col block = one head
    const int which = colb >> 10;             // 0=Q 1=K 2=V (wave-uniform)
    const int h2 = (colb >> 6) & 15;
    const float scl = (which == 0) ? 0.18033688f : 1.0f;   // /sqrt(64)*log2e
#pragma unroll
    for (int mi = 0; mi < 4; ++mi)
#pragma unroll
        for (int ni = 0; ni < 4; ++ni) {
            const int col = colb + ni * 16 + l15;
            const float bv = isb ? b2f(((const unsigned short*)bias)[col])
                                 : ((const float*)bias)[col];
#pragma unroll
            for (int r = 0; r < 4; ++r)
                Ot[mi * 16 + l4 * 4 + r][ni * 16 + l15] =
                    f2b((acc[mi][ni][r] + bv) * scl);
        }
    asm volatile("" ::: "memory");   // LDS write -> read (same wave)
    unsigned short* dst = (which == 0) ? outQ : ((which == 1) ? outK : outV);
    const int tr = lane >> 3, tc = lane & 7;
#pragma unroll
    for (int p = 0; p < 8; ++p) {
        const int row = bm + wm + p * 8 + tr;
        const int b = row >> 11, t = row & 2047;
        u16x8 o = *(const u16x8*)&Ot[p * 8 + tr][tc * 8];
        *(u16x8*)(dst + (((size_t)b * HH + h2) * TT + t) * DD + tc * 8) = o;
    }
}

// ---------------- flash attention v8: v6 + V-load hoisted to iteration top ----------------
// V fragments are independent of everything in-iteration; issuing them FIRST
// covers their ~200-300cy L2 latency under QK_A + sm_A + QK_B + sm_B instead
// of ~100cy. VGPR-peak-neutral (peak is at PV where vf is live either way).
__global__ __launch_bounds__(256) void attn_k(unsigned short* __restrict__ Q,
                                              const unsigned short* __restrict__ K,
                                              const unsigned short* __restrict__ VT) {
    __shared__ __align__(16) char shmem[32000];
    const int tid = threadIdx.x, lane = tid & 63, h = tid >> 6;
    const int bid = blockIdx.x;
    const int swb = (bid & 7) * 256 + (bid >> 3);   // XCD swizzle (2048%8==0)
    const int bh = swb >> 5;
    const int pair = swb & 31;
    const int l15 = lane & 15, l4 = lane >> 4;
    unsigned short* Qp = Q + (size_t)bh * TT * DD;
    const unsigned short* Kp = K + (size_t)bh * TT * DD;
    const unsigned short* Vp = VT + (size_t)bh * DD * TT;
    const int swz = (l15 & 7) << 4;
    unsigned short (*PldsW)[64] = (unsigned short (*)[64])(shmem + h * 4096);
    unsigned char* prowA = (unsigned char*)&PldsW[l15][0];
    unsigned char* prowB = (unsigned char*)&PldsW[16 + l15][0];
    float* MrgF = (float*)shmem;
    unsigned short (*Olds)[34] = (unsigned short (*)[34])(shmem + 27648);

#pragma unroll 1
    for (int hv = 0; hv < 2; ++hv) {
        const int qt = hv ? (63 - pair) : pair;
        const int qw = qt << 5;
        const int qiA = qw + l15, qiB = qw + 16 + l15;
        const int kend = qw + 32;

        short8 qfA0 = *(const short8*)(Qp + (size_t)(qw + l15) * DD + l4 * 8);
        short8 qfA1 = *(const short8*)(Qp + (size_t)(qw + l15) * DD + 32 + l4 * 8);
        short8 qfB0 = *(const short8*)(Qp + (size_t)(qw + 16 + l15) * DD + l4 * 8);
        short8 qfB1 = *(const short8*)(Qp + (size_t)(qw + 16 + l15) * DD + 32 + l4 * 8);

        f32x4 otA[4], otB[4];
#pragma unroll
        for (int c = 0; c < 4; ++c) {
            otA[c] = (f32x4){0.f, 0.f, 0.f, 0.f};
            otB[c] = (f32x4){0.f, 0.f, 0.f, 0.f};
        }
        float mA = -1e30f, lA = 0.f, mB = -1e30f, lB = 0.f;

        auto softmax16 = [&](f32x4 (&st)[4], float& m, float& lsum, f32x4 (&ot)[4],
                             int qi, bool needMask, int kb, unsigned char* prow) {
            if (needMask) {
#pragma unroll
                for (int t = 0; t < 4; ++t)
#pragma unroll
                    for (int r = 0; r < 4; ++r) {
                        const int kpos = kb + t * 16 + l4 * 4 + r;
                        st[t][r] = (kpos > qi) ? -30000.f : st[t][r];
                    }
            }
            float mx0 = fmaxf(fmaxf(st[0][0], st[0][1]), fmaxf(st[0][2], st[0][3]));
            float mx1 = fmaxf(fmaxf(st[1][0], st[1][1]), fmaxf(st[1][2], st[1][3]));
            float mx2 = fmaxf(fmaxf(st[2][0], st[2][1]), fmaxf(st[2][2], st[2][3]));
            float mx3 = fmaxf(fmaxf(st[3][0], st[3][1]), fmaxf(st[3][2], st[3][3]));
            float tmax = fmaxf(fmaxf(mx0, mx1), fmaxf(mx2, mx3));
            tmax = fmaxf(tmax, __shfl_xor(tmax, 16));
            tmax = fmaxf(tmax, __shfl_xor(tmax, 32));
            if (!__all(tmax <= m + 8.f)) {       // T13 defer-max
                const float mnew = fmaxf(m, tmax);
                const float corr = exp2_hw(m - mnew);
                lsum *= corr;
#pragma unroll
                for (int c = 0; c < 4; ++c) ot[c] *= corr;
                m = mnew;
            }
            u16x4 pw[4];
            float s0 = 0.f, s1 = 0.f, s2 = 0.f, s3 = 0.f;
#pragma unroll
            for (int t = 0; t < 4; ++t)
#pragma unroll
                for (int r = 0; r < 4; ++r) {
                    float p = exp2_hw(st[t][r] - m);
                    if (t == 0) s0 += p; else if (t == 1) s1 += p;
                    else if (t == 2) s2 += p; else s3 += p;
                    pw[t][r] = f2b_hw(p);        // native cvt (pairs fuse)
                }
            lsum += (s0 + s1) + (s2 + s3);
#pragma unroll
            for (int t = 0; t < 4; ++t)
                *(u16x4*)(prow + ((t * 32 + l4 * 8) ^ swz)) = pw[t];
        };

        // prologue: load first K tile
        short8 kf[4][2];
        {
            const int kb0 = h * 64;
            if (kb0 < kend) {
#pragma unroll
                for (int t = 0; t < 4; ++t) {
                    const unsigned short* kr = Kp + (size_t)(kb0 + t * 16 + l15) * DD + l4 * 8;
                    kf[t][0] = *(const short8*)(kr);
                    kf[t][1] = *(const short8*)(kr + 32);
                }
            }
        }

#pragma unroll 1
        for (int kb = h * 64; kb < kend; kb += 256) {
            // V for this iteration FIRST: independent loads, consumed only at
            // PV -> latency hidden under QK_A + sm_A + QK_B + prefetch + sm_B
            short8 vf[4][2];
#pragma unroll
            for (int c = 0; c < 4; ++c)
#pragma unroll
                for (int ch = 0; ch < 2; ++ch)
                    vf[c][ch] = *(const short8*)(Vp + (size_t)(c * 16 + l15) * TT
                                                 + kb + ch * 32 + l4 * 8);
            // QK^T subtile A (uses prefetched kf)
            f32x4 st[4];
            __builtin_amdgcn_s_setprio(1);
#pragma unroll
            for (int t = 0; t < 4; ++t) {
                f32x4 z = (f32x4){0.f, 0.f, 0.f, 0.f};
                z = __builtin_amdgcn_mfma_f32_16x16x32_bf16(kf[t][0], qfA0, z, 0, 0, 0);
                z = __builtin_amdgcn_mfma_f32_16x16x32_bf16(kf[t][1], qfA1, z, 0, 0, 0);
                st[t] = z;
            }
            __builtin_amdgcn_s_setprio(0);
            softmax16(st, mA, lA, otA, qiA, kb + 63 > qw, kb, prowA);
            // QK^T subtile B (last consumer of kf)
            __builtin_amdgcn_s_setprio(1);
#pragma unroll
            for (int t = 0; t < 4; ++t) {
                f32x4 z = (f32x4){0.f, 0.f, 0.f, 0.f};
                z = __builtin_amdgcn_mfma_f32_16x16x32_bf16(kf[t][0], qfB0, z, 0, 0, 0);
                z = __builtin_amdgcn_mfma_f32_16x16x32_bf16(kf[t][1], qfB1, z, 0, 0, 0);
                st[t] = z;
            }
            __builtin_amdgcn_s_setprio(0);
            // prefetch next iteration's K into the SAME regs (kf dead now)
            const int kbn = kb + 256;
            if (kbn < kend) {
#pragma unroll
                for (int t = 0; t < 4; ++t) {
                    const unsigned short* kr = Kp + (size_t)(kbn + t * 16 + l15) * DD + l4 * 8;
                    kf[t][0] = *(const short8*)(kr);
                    kf[t][1] = *(const short8*)(kr + 32);
                }
            }
            softmax16(st, mB, lB, otB, qiB, kb + 63 > qw + 16, kb, prowB);
            asm volatile("" ::: "memory");
            short8 pbA0 = *(const short8*)(prowA + ((l4 * 16) ^ swz));
            short8 pbA1 = *(const short8*)(prowA + ((64 + l4 * 16) ^ swz));
            short8 pbB0 = *(const short8*)(prowB + ((l4 * 16) ^ swz));
            short8 pbB1 = *(const short8*)(prowB + ((64 + l4 * 16) ^ swz));
            asm volatile("" ::: "memory");
            __builtin_amdgcn_s_setprio(1);
#pragma unroll
            for (int c = 0; c < 4; ++c) {
                otA[c] = __builtin_amdgcn_mfma_f32_16x16x32_bf16(vf[c][0], pbA0, otA[c], 0, 0, 0);
                otA[c] = __builtin_amdgcn_mfma_f32_16x16x32_bf16(vf[c][1], pbA1, otA[c], 0, 0, 0);
                otB[c] = __builtin_amdgcn_mfma_f32_16x16x32_bf16(vf[c][0], pbB0, otB[c], 0, 0, 0);
                otB[c] = __builtin_amdgcn_mfma_f32_16x16x32_bf16(vf[c][1], pbB1, otB[c], 0, 0, 0);
            }
            __builtin_amdgcn_s_setprio(0);
        }

        float lsA = lA + __shfl_xor(lA, 16);
        lsA += __shfl_xor(lsA, 32);
        float lsB = lB + __shfl_xor(lB, 16);
        lsB += __shfl_xor(lsB, 32);

        __syncthreads();
        if (h > 0) {
            float* mb = MrgF + ((size_t)(h - 1) * 64 + lane) * 36;
            mb[0] = mA; mb[1] = lsA; mb[2] = mB; mb[3] = lsB;
#pragma unroll
            for (int c = 0; c < 4; ++c)
#pragma unroll
                for (int r = 0; r < 4; ++r) {
                    mb[4 + c * 4 + r]  = otA[c][r];
                    mb[20 + c * 4 + r] = otB[c][r];
                }
        }
        __syncthreads();
        if (h == 0) {
            auto merge16 = [&](float m0, float ls0, const f32x4 (&ot)[4],
                               int mOff, int oOff, int col) {
                float mj[3], lj[3];
                float mstar = m0;
#pragma unroll
                for (int j = 0; j < 3; ++j) {
                    mj[j] = MrgF[((size_t)j * 64 + lane) * 36 + mOff];
                    lj[j] = MrgF[((size_t)j * 64 + lane) * 36 + mOff + 1];
                    mstar = fmaxf(mstar, mj[j]);
                }
                const float cs = exp2_hw(m0 - mstar);
                float cj[3];
                float den = ls0 * cs;
#pragma unroll
                for (int j = 0; j < 3; ++j) {
                    cj[j] = exp2_hw(mj[j] - mstar);
                    den += lj[j] * cj[j];
                }
                const float inv = 1.f / den;
#pragma unroll
                for (int c = 0; c < 4; ++c)
#pragma unroll
                    for (int r = 0; r < 4; ++r) {
                        float v = ot[c][r] * cs;
#pragma unroll
                        for (int j = 0; j < 3; ++j)
                            v += MrgF[((size_t)j * 64 + lane) * 36 + oOff + c * 4 + r] * cj[j];
                        v *= inv;
                        if (!finite_f(v)) v = 200.0f;   // canary
                        Olds[c * 16 + l4 * 4 + r][col] = f2b(v);
                    }
            };
            merge16(mA, lsA, otA, 0, 4, l15);
            merge16(mB, lsB, otB, 2, 20, 16 + l15);
            asm volatile("" ::: "memory");
            const int qr = lane >> 1, hf = lane & 1;
#pragma unroll
            for (int chunk = 0; chunk < 4; ++chunk) {
                u16x8 o;
#pragma unroll
                for (int j = 0; j < 8; ++j) o[j] = Olds[hf * 32 + chunk * 8 + j][qr];
                *(u16x8*)(Qp + (size_t)(qw + qr) * DD + hf * 32 + chunk * 8) = o;
            }
        }
        __syncthreads();
    }
}

// -------- proj GEMM: Y([b][h][t][d] in Q region) @ WprojT + bias -> out fp32 --------
__global__ __launch_bounds__(256) void gemm_proj(const unsigned short* __restrict__ A,
                                                 const unsigned short* __restrict__ Bt,
                                                 const void* __restrict__ bias,
                                                 float* __restrict__ outO,
                                                 const int* __restrict__ flag) {
    __shared__ unsigned short As[128 * 64];
    __shared__ unsigned short Bs[128 * 64];
    const int Ksz = CCH;
    const int tid = threadIdx.x;
    const int lane = tid & 63;
    const int wid = tid >> 6;
    const int bm = blockIdx.y * 128;
    const int bn = blockIdx.x * 128;
    const int wm = (wid >> 1) * 64;
    const int wn = (wid & 1) * 64;
    const int r8 = tid >> 3;
    const int c8 = tid & 7;
    const int cg = c8 ^ (r8 & 7);
    const int l15 = lane & 15, l4 = lane >> 4;
    const int isb = *flag;

    f32x4 acc[4][4];
#pragma unroll
    for (int i = 0; i < 4; ++i)
#pragma unroll
        for (int j = 0; j < 4; ++j)
            acc[i][j] = (f32x4){0.f, 0.f, 0.f, 0.f};

    const unsigned short* pac[4];
    const unsigned short* pbc[4];
    unsigned short* lac[4];
    unsigned short* lbc[4];
#pragma unroll
    for (int ch = 0; ch < 4; ++ch) {
        const int m = bm + ch * 32 + r8;
        pac[ch] = A + (size_t)(m >> 11) * (HH * TT * DD)
                    + (size_t)(m & 2047) * DD + cg * 8;
        pbc[ch] = Bt + (size_t)(bn + ch * 32 + r8) * Ksz + cg * 8;
        lac[ch] = &As[ch * 2048 + tid * 8];
        lbc[ch] = &Bs[ch * 2048 + tid * 8];
    }

    for (int kt = 0; kt < Ksz; kt += 64) {
        const size_t aoff = (size_t)(kt >> 6) * (TT * DD);
        __syncthreads();
#pragma unroll
        for (int ch = 0; ch < 4; ++ch) gl_lds16(pac[ch] + aoff, lac[ch]);
#pragma unroll
        for (int ch = 0; ch < 4; ++ch) gl_lds16(pbc[ch] + kt, lbc[ch]);
        __syncthreads();
#pragma unroll
        for (int kk = 0; kk < 2; ++kk) {
            short8 af[4], bfr[4];
#pragma unroll
            for (int mi = 0; mi < 4; ++mi)
                af[mi] = *(const short8*)&As[(wm + mi * 16 + l15) * 64
                                             + (((l4 + kk * 4) ^ (l15 & 7)) * 8)];
#pragma unroll
            for (int ni = 0; ni < 4; ++ni)
                bfr[ni] = *(const short8*)&Bs[(wn + ni * 16 + l15) * 64
                                              + (((l4 + kk * 4) ^ (l15 & 7)) * 8)];
#pragma unroll
            for (int mi = 0; mi < 4; ++mi)
#pragma unroll
                for (int ni = 0; ni < 4; ++ni)
                    acc[mi][ni] = __builtin_amdgcn_mfma_f32_16x16x32_bf16(
                        af[mi], bfr[ni], acc[mi][ni], 0, 0, 0);
        }
    }

#pragma unroll
    for (int mi = 0; mi < 4; ++mi) {
#pragma unroll
        for (int ni = 0; ni < 4; ++ni) {
            const int col = bn + wn + ni * 16 + l15;
            const float bv = isb ? b2f(((const unsigned short*)bias)[col])
                                 : ((const float*)bias)[col];
#pragma unroll
            for (int r = 0; r < 4; ++r) {
                const int row = bm + wm + mi * 16 + l4 * 4 + r;
                float v = acc[mi][ni][r] + bv;
                if (!finite_f(v)) v = 300.0f;   // canary
                outO[(size_t)row * CCH + col] = v;
            }
        }
    }
}

extern "C" void kernel_launch(void* const* d_in, const int* in_sizes, int n_in,
                              void* d_out, int out_size, void* d_ws, size_t ws_size,
                              hipStream_t stream) {
    const void* x     = d_in[0];
    const void* Wqkv  = d_in[1];
    const void* bqkv  = d_in[2];
    const void* Wproj = d_in[3];
    const void* bproj = d_in[4];
    float* out = (float*)d_out;

    // workspace: 58.7 MB; d_out doubles as scratch: [xb 16.78MB | Vstage 16.78MB]
    char* w = (char*)d_ws;
    int* flag = (int*)w;                          w += 256;
    unsigned short* wqkvT  = (unsigned short*)w;  w += (size_t)3 * CCH * CCH * 2;
    unsigned short* wprojT = (unsigned short*)w;  w += (size_t)CCH * CCH * 2;
    unsigned short* Qb     = (unsigned short*)w;  w += (size_t)MM * CCH * 2;
    unsigned short* Kb     = (unsigned short*)w;  w += (size_t)MM * CCH * 2;
    unsigned short* VTb    = (unsigned short*)w;  w += (size_t)MM * CCH * 2;
    unsigned short* xb     = (unsigned short*)d_out;
    unsigned short* Vstage = (unsigned short*)d_out + (size_t)MM * CCH;

    detect_k<<<1, 64, 0, stream>>>((const unsigned int*)x, flag);
    cast_x_k<<<MM * CCH / 8 / 256, 256, 0, stream>>>(x, xb, flag);
    wtrans_k<<<dim3(96, 32), 256, 0, stream>>>(Wqkv, wqkvT, CCH, 3 * CCH, flag);
    wtrans_k<<<dim3(32, 32), 256, 0, stream>>>(Wproj, wprojT, CCH, CCH, flag);
    gemm_qkv<<<dim3(24, 64), 256, 0, stream>>>(xb, wqkvT, bqkv, Qb, Kb, Vstage, flag);
    vtrans_k<<<dim3(32, 64), 256, 0, stream>>>(Vstage, VTb);
    attn_k<<<2048, 256, 0, stream>>>(Qb, Kb, VTb);          // writes Y over Q rows
    gemm_proj<<<dim3(8, 64), 256, 0, stream>>>(Qb, wprojT, bproj, out, flag);
}

// Round 19
// 266.874 us; speedup vs baseline: 1.0339x; 1.0339x over previous
//
#include <hip/hip_runtime.h>
#include <hip/hip_bf16.h>

#define TT 2048
#define CCH 1024
#define HH 16
#define DD 64
#define BB 4
#define MM (BB*TT)

typedef __attribute__((ext_vector_type(4))) float f32x4;
typedef __attribute__((ext_vector_type(8))) short short8;
typedef __attribute__((ext_vector_type(8))) unsigned short u16x8;
typedef __attribute__((ext_vector_type(4))) unsigned short u16x4;

__device__ __forceinline__ unsigned short f2b(float f) {
    unsigned int u = __float_as_uint(f);
    u += 0x7fffu + ((u >> 16) & 1u);
    return (unsigned short)(u >> 16);
}
// native HW convert (compiler emits v_cvt_pk_bf16_f32 for pairs)
__device__ __forceinline__ unsigned short f2b_hw(float f) {
    __hip_bfloat16 h = __float2bfloat16(f);
    return reinterpret_cast<unsigned short&>(h);
}
__device__ __forceinline__ float b2f(unsigned short u) {
    return __uint_as_float(((unsigned int)u) << 16);
}
__device__ __forceinline__ int finite_f(float v) {
    return ((__float_as_uint(v) >> 23) & 0xFFu) != 0xFFu;
}
__device__ __forceinline__ float exp2_hw(float x) {
    return __builtin_amdgcn_exp2f(x);
}

// async global->LDS, 16B per lane (dest must be wave-uniform base + lane*16)
typedef const __attribute__((address_space(1))) unsigned int g_u32;
typedef __attribute__((address_space(3))) unsigned int l_u32;
__device__ __forceinline__ void gl_lds16(const unsigned short* g, unsigned short* l) {
    __builtin_amdgcn_global_load_lds((g_u32*)g, (l_u32*)l, 16, 0, 0);
}

// ---------------- fused prepass: dtype-detect + cast_x + both W transposes ----------------
// blocks [0,4096): cast x chunk; [4096,7168): Wqkv trans; [7168,8192): Wproj trans.
// Each block computes the bf16/fp32 flag LOCALLY from x's first 4KB (L2-hot);
// block 0 publishes it for the downstream GEMM bias branches.
__global__ __launch_bounds__(256) void prepass_k(const void* __restrict__ x,
                                                 const void* __restrict__ Wqkv,
                                                 const void* __restrict__ Wproj,
                                                 unsigned short* __restrict__ xb,
                                                 unsigned short* __restrict__ wqkvT,
                                                 unsigned short* __restrict__ wprojT,
                                                 int* __restrict__ flag) {
    __shared__ int cnts[4];
    __shared__ float tile[32][33];
    const int tid = threadIdx.x, lane = tid & 63, wid = tid >> 6;
    {   // local dtype detect: 256 threads x 4 u32 words
        const unsigned int* xw = (const unsigned int*)x;
        int cnt = 0;
#pragma unroll
        for (int i = 0; i < 4; ++i) {
            unsigned int w = xw[tid * 4 + i];
            unsigned int lo = w & 0xFFFFu;
            unsigned int e = (lo >> 7) & 0xFFu;
            if ((e >= 0x62u && e <= 0x90u) || lo == 0u) ++cnt;
        }
#pragma unroll
        for (int o = 32; o; o >>= 1) cnt += __shfl_down(cnt, o);
        if (lane == 0) cnts[wid] = cnt;
    }
    __syncthreads();
    const int isb = (cnts[0] + cnts[1] + cnts[2] + cnts[3]) >= 640;   // of 1024
    const int bid = blockIdx.x;
    if (bid == 0 && tid == 0) *flag = isb;

    if (bid < 4096) {                       // ---- cast/copy x -> bf16 ----
        const size_t g = (size_t)bid * 256 + tid;
        if (isb) {
            *(u16x8*)(xb + g * 8) =
                *(const u16x8*)((const unsigned short*)x + g * 8);
        } else {
            const float4* p = (const float4*)((const float*)x + g * 8);
            float4 v0 = p[0], v1 = p[1];
            u16x8 o;
            o[0] = f2b(v0.x); o[1] = f2b(v0.y); o[2] = f2b(v0.z); o[3] = f2b(v0.w);
            o[4] = f2b(v1.x); o[5] = f2b(v1.y); o[6] = f2b(v1.z); o[7] = f2b(v1.w);
            *(u16x8*)(xb + g * 8) = o;
        }
    } else {                                // ---- W transpose(+cast) ----
        const void* in;
        unsigned short* out;
        int R = CCH, Cc, bx, by;
        if (bid < 4096 + 3072) {
            in = Wqkv; out = wqkvT; Cc = 3 * CCH;
            const int i = bid - 4096; bx = i % 96; by = i / 96;
        } else {
            in = Wproj; out = wprojT; Cc = CCH;
            const int i = bid - 7168; bx = i % 32; by = i / 32;
        }
        const int c0 = bx * 32, r0 = by * 32;
#pragma unroll
        for (int i = 0; i < 4; ++i) {
            int e = i * 256 + tid;
            int row = e >> 5, col = e & 31;
            size_t idx = (size_t)(r0 + row) * Cc + (c0 + col);
            tile[row][col] = isb ? b2f(((const unsigned short*)in)[idx])
                                 : ((const float*)in)[idx];
        }
        __syncthreads();
#pragma unroll
        for (int i = 0; i < 4; ++i) {
            int e = i * 256 + tid;
            int crow = e >> 5, rcol = e & 31;
            out[(size_t)(c0 + crow) * R + (r0 + rcol)] = f2b(tile[rcol][crow]);
        }
    }
}

// ------------- V transpose: bf16 [bh][2048][64] -> [bh][64][2048] -------------
__global__ __launch_bounds__(256) void vtrans_k(const unsigned short* __restrict__ V,
                                                unsigned short* __restrict__ VT) {
    __shared__ unsigned short tile[64][68];
    const int tid = threadIdx.x;
    const int t0 = blockIdx.x * 64;
    const int bh = blockIdx.y;
    const unsigned short* in = V + ((size_t)bh * TT + t0) * DD;
#pragma unroll
    for (int i = 0; i < 4; ++i) {
        int cid = i * 256 + tid;
        int row = cid >> 4;
        int ch  = cid & 15;
        u16x4 v = *(const u16x4*)(in + row * DD + ch * 4);
        *(u16x4*)&tile[row][ch * 4] = v;
    }
    __syncthreads();
    unsigned short* out = VT + (size_t)bh * DD * TT + t0;
#pragma unroll
    for (int i = 0; i < 4; ++i) {
        int cid = i * 256 + tid;
        int drow = cid >> 4;
        int tch  = cid & 15;
        u16x4 v;
        v[0] = tile[tch * 4 + 0][drow];
        v[1] = tile[tch * 4 + 1][drow];
        v[2] = tile[tch * 4 + 2][drow];
        v[3] = tile[tch * 4 + 3][drow];
        *(u16x4*)(out + (size_t)drow * TT + tch * 4) = v;
    }
}

// -------- QKV GEMM: xb[M][K] bf16 @ WqkvT[N][K] bf16 + bias --------
// BK=64 gl_lds staging (source-swizzled) + LDS-staged coalesced epilogue.
__global__ __launch_bounds__(256) void gemm_qkv(const unsigned short* __restrict__ A,
                                                const unsigned short* __restrict__ Bt,
                                                const void* __restrict__ bias,
                                                unsigned short* __restrict__ outQ,
                                                unsigned short* __restrict__ outK,
                                                unsigned short* __restrict__ outV,
                                                const int* __restrict__ flag) {
    __shared__ __align__(16) char smem[34816];   // As 16K | Bs 16K; epi: 4x8704
    unsigned short* As = (unsigned short*)smem;
    unsigned short* Bs = (unsigned short*)(smem + 16384);
    const int Ksz = CCH;
    const int tid = threadIdx.x;
    const int lane = tid & 63;
    const int wid = tid >> 6;
    const int bm = blockIdx.y * 128;
    const int bn = blockIdx.x * 128;
    const int wm = (wid >> 1) * 64;
    const int wn = (wid & 1) * 64;
    const int r8 = tid >> 3;            // 0..31
    const int c8 = tid & 7;             // granule slot
    const int cg = c8 ^ (r8 & 7);       // swizzled source granule
    const int l15 = lane & 15, l4 = lane >> 4;
    const int isb = *flag;

    f32x4 acc[4][4];
#pragma unroll
    for (int i = 0; i < 4; ++i)
#pragma unroll
        for (int j = 0; j < 4; ++j)
            acc[i][j] = (f32x4){0.f, 0.f, 0.f, 0.f};

    const unsigned short* pac[4];
    const unsigned short* pbc[4];
    unsigned short* lac[4];
    unsigned short* lbc[4];
#pragma unroll
    for (int ch = 0; ch < 4; ++ch) {
        pac[ch] = A  + (size_t)(bm + ch * 32 + r8) * Ksz + cg * 8;
        pbc[ch] = Bt + (size_t)(bn + ch * 32 + r8) * Ksz + cg * 8;
        lac[ch] = &As[ch * 2048 + tid * 8];   // linear dest (byte = 16*tid)
        lbc[ch] = &Bs[ch * 2048 + tid * 8];
    }

    for (int kt = 0; kt < Ksz; kt += 64) {
        __syncthreads();
#pragma unroll
        for (int ch = 0; ch < 4; ++ch) gl_lds16(pac[ch] + kt, lac[ch]);
#pragma unroll
        for (int ch = 0; ch < 4; ++ch) gl_lds16(pbc[ch] + kt, lbc[ch]);
        __syncthreads();
#pragma unroll
        for (int kk = 0; kk < 2; ++kk) {
            short8 af[4], bfr[4];
#pragma unroll
            for (int mi = 0; mi < 4; ++mi)
                af[mi] = *(const short8*)&As[(wm + mi * 16 + l15) * 64
                                             + (((l4 + kk * 4) ^ (l15 & 7)) * 8)];
#pragma unroll
            for (int ni = 0; ni < 4; ++ni)
                bfr[ni] = *(const short8*)&Bs[(wn + ni * 16 + l15) * 64
                                              + (((l4 + kk * 4) ^ (l15 & 7)) * 8)];
#pragma unroll
            for (int mi = 0; mi < 4; ++mi)
#pragma unroll
                for (int ni = 0; ni < 4; ++ni)
                    acc[mi][ni] = __builtin_amdgcn_mfma_f32_16x16x32_bf16(
                        af[mi], bfr[ni], acc[mi][ni], 0, 0, 0);
        }
    }

    // ---- coalesced epilogue via LDS (reuse staging space; As/Bs dead) ----
    __syncthreads();   // all waves done with fragment reads
    unsigned short (*Ot)[68] = (unsigned short (*)[68])(smem + wid * 8704);
    const int colb = bn + wn;                 // wave's 64-col block = one head
    const int which = colb >> 10;             // 0=Q 1=K 2=V (wave-uniform)
    const int h2 = (colb >> 6) & 15;
    const float scl = (which == 0) ? 0.18033688f : 1.0f;   // /sqrt(64)*log2e
#pragma unroll
    for (int mi = 0; mi < 4; ++mi)
#pragma unroll
        for (int ni = 0; ni < 4; ++ni) {
            const int col = colb + ni * 16 + l15;
            const float bv = isb ? b2f(((const unsigned short*)bias)[col])
                                 : ((const float*)bias)[col];
#pragma unroll
            for (int r = 0; r < 4; ++r)
                Ot[mi * 16 + l4 * 4 + r][ni * 16 + l15] =
                    f2b((acc[mi][ni][r] + bv) * scl);
        }
    asm volatile("" ::: "memory");   // LDS write -> read (same wave)
    unsigned short* dst = (which == 0) ? outQ : ((which == 1) ? outK : outV);
    const int tr = lane >> 3, tc = lane & 7;
#pragma unroll
    for (int p = 0; p < 8; ++p) {
        const int row = bm + wm + p * 8 + tr;
        const int b = row >> 11, t = row & 2047;
        u16x8 o = *(const u16x8*)&Ot[p * 8 + tr][tc * 8];
        *(u16x8*)(dst + (((size_t)b * HH + h2) * TT + t) * DD + tc * 8) = o;
    }
}

// ---------------- flash attention v8 (round 18 structure) ----------------
__global__ __launch_bounds__(256) void attn_k(unsigned short* __restrict__ Q,
                                              const unsigned short* __restrict__ K,
                                              const unsigned short* __restrict__ VT) {
    __shared__ __align__(16) char shmem[32000];
    const int tid = threadIdx.x, lane = tid & 63, h = tid >> 6;
    const int bid = blockIdx.x;
    const int swb = (bid & 7) * 256 + (bid >> 3);   // XCD swizzle (2048%8==0)
    const int bh = swb >> 5;
    const int pair = swb & 31;
    const int l15 = lane & 15, l4 = lane >> 4;
    unsigned short* Qp = Q + (size_t)bh * TT * DD;
    const unsigned short* Kp = K + (size_t)bh * TT * DD;
    const unsigned short* Vp = VT + (size_t)bh * DD * TT;
    const int swz = (l15 & 7) << 4;
    unsigned short (*PldsW)[64] = (unsigned short (*)[64])(shmem + h * 4096);
    unsigned char* prowA = (unsigned char*)&PldsW[l15][0];
    unsigned char* prowB = (unsigned char*)&PldsW[16 + l15][0];
    float* MrgF = (float*)shmem;
    unsigned short (*Olds)[34] = (unsigned short (*)[34])(shmem + 27648);

#pragma unroll 1
    for (int hv = 0; hv < 2; ++hv) {
        const int qt = hv ? (63 - pair) : pair;
        const int qw = qt << 5;
        const int qiA = qw + l15, qiB = qw + 16 + l15;
        const int kend = qw + 32;

        short8 qfA0 = *(const short8*)(Qp + (size_t)(qw + l15) * DD + l4 * 8);
        short8 qfA1 = *(const short8*)(Qp + (size_t)(qw + l15) * DD + 32 + l4 * 8);
        short8 qfB0 = *(const short8*)(Qp + (size_t)(qw + 16 + l15) * DD + l4 * 8);
        short8 qfB1 = *(const short8*)(Qp + (size_t)(qw + 16 + l15) * DD + 32 + l4 * 8);

        f32x4 otA[4], otB[4];
#pragma unroll
        for (int c = 0; c < 4; ++c) {
            otA[c] = (f32x4){0.f, 0.f, 0.f, 0.f};
            otB[c] = (f32x4){0.f, 0.f, 0.f, 0.f};
        }
        float mA = -1e30f, lA = 0.f, mB = -1e30f, lB = 0.f;

        auto softmax16 = [&](f32x4 (&st)[4], float& m, float& lsum, f32x4 (&ot)[4],
                             int qi, bool needMask, int kb, unsigned char* prow) {
            if (needMask) {
#pragma unroll
                for (int t = 0; t < 4; ++t)
#pragma unroll
                    for (int r = 0; r < 4; ++r) {
                        const int kpos = kb + t * 16 + l4 * 4 + r;
                        st[t][r] = (kpos > qi) ? -30000.f : st[t][r];
                    }
            }
            float mx0 = fmaxf(fmaxf(st[0][0], st[0][1]), fmaxf(st[0][2], st[0][3]));
            float mx1 = fmaxf(fmaxf(st[1][0], st[1][1]), fmaxf(st[1][2], st[1][3]));
            float mx2 = fmaxf(fmaxf(st[2][0], st[2][1]), fmaxf(st[2][2], st[2][3]));
            float mx3 = fmaxf(fmaxf(st[3][0], st[3][1]), fmaxf(st[3][2], st[3][3]));
            float tmax = fmaxf(fmaxf(mx0, mx1), fmaxf(mx2, mx3));
            tmax = fmaxf(tmax, __shfl_xor(tmax, 16));
            tmax = fmaxf(tmax, __shfl_xor(tmax, 32));
            if (!__all(tmax <= m + 8.f)) {       // T13 defer-max
                const float mnew = fmaxf(m, tmax);
                const float corr = exp2_hw(m - mnew);
                lsum *= corr;
#pragma unroll
                for (int c = 0; c < 4; ++c) ot[c] *= corr;
                m = mnew;
            }
            u16x4 pw[4];
            float s0 = 0.f, s1 = 0.f, s2 = 0.f, s3 = 0.f;
#pragma unroll
            for (int t = 0; t < 4; ++t)
#pragma unroll
                for (int r = 0; r < 4; ++r) {
                    float p = exp2_hw(st[t][r] - m);
                    if (t == 0) s0 += p; else if (t == 1) s1 += p;
                    else if (t == 2) s2 += p; else s3 += p;
                    pw[t][r] = f2b_hw(p);        // native cvt (pairs fuse)
                }
            lsum += (s0 + s1) + (s2 + s3);
#pragma unroll
            for (int t = 0; t < 4; ++t)
                *(u16x4*)(prow + ((t * 32 + l4 * 8) ^ swz)) = pw[t];
        };

        // prologue: load first K tile
        short8 kf[4][2];
        {
            const int kb0 = h * 64;
            if (kb0 < kend) {
#pragma unroll
                for (int t = 0; t < 4; ++t) {
                    const unsigned short* kr = Kp + (size_t)(kb0 + t * 16 + l15) * DD + l4 * 8;
                    kf[t][0] = *(const short8*)(kr);
                    kf[t][1] = *(const short8*)(kr + 32);
                }
            }
        }

#pragma unroll 1
        for (int kb = h * 64; kb < kend; kb += 256) {
            // V first: independent loads, consumed only at PV
            short8 vf[4][2];
#pragma unroll
            for (int c = 0; c < 4; ++c)
#pragma unroll
                for (int ch = 0; ch < 2; ++ch)
                    vf[c][ch] = *(const short8*)(Vp + (size_t)(c * 16 + l15) * TT
                                                 + kb + ch * 32 + l4 * 8);
            // QK^T subtile A (uses prefetched kf)
            f32x4 st[4];
            __builtin_amdgcn_s_setprio(1);
#pragma unroll
            for (int t = 0; t < 4; ++t) {
                f32x4 z = (f32x4){0.f, 0.f, 0.f, 0.f};
                z = __builtin_amdgcn_mfma_f32_16x16x32_bf16(kf[t][0], qfA0, z, 0, 0, 0);
                z = __builtin_amdgcn_mfma_f32_16x16x32_bf16(kf[t][1], qfA1, z, 0, 0, 0);
                st[t] = z;
            }
            __builtin_amdgcn_s_setprio(0);
            softmax16(st, mA, lA, otA, qiA, kb + 63 > qw, kb, prowA);
            // QK^T subtile B (last consumer of kf)
            __builtin_amdgcn_s_setprio(1);
#pragma unroll
            for (int t = 0; t < 4; ++t) {
                f32x4 z = (f32x4){0.f, 0.f, 0.f, 0.f};
                z = __builtin_amdgcn_mfma_f32_16x16x32_bf16(kf[t][0], qfB0, z, 0, 0, 0);
                z = __builtin_amdgcn_mfma_f32_16x16x32_bf16(kf[t][1], qfB1, z, 0, 0, 0);
                st[t] = z;
            }
            __builtin_amdgcn_s_setprio(0);
            // prefetch next iteration's K into the SAME regs (kf dead now)
            const int kbn = kb + 256;
            if (kbn < kend) {
#pragma unroll
                for (int t = 0; t < 4; ++t) {
                    const unsigned short* kr = Kp + (size_t)(kbn + t * 16 + l15) * DD + l4 * 8;
                    kf[t][0] = *(const short8*)(kr);
                    kf[t][1] = *(const short8*)(kr + 32);
                }
            }
            softmax16(st, mB, lB, otB, qiB, kb + 63 > qw + 16, kb, prowB);
            asm volatile("" ::: "memory");
            short8 pbA0 = *(const short8*)(prowA + ((l4 * 16) ^ swz));
            short8 pbA1 = *(const short8*)(prowA + ((64 + l4 * 16) ^ swz));
            short8 pbB0 = *(const short8*)(prowB + ((l4 * 16) ^ swz));
            short8 pbB1 = *(const short8*)(prowB + ((64 + l4 * 16) ^ swz));
            asm volatile("" ::: "memory");
            __builtin_amdgcn_s_setprio(1);
#pragma unroll
            for (int c = 0; c < 4; ++c) {
                otA[c] = __builtin_amdgcn_mfma_f32_16x16x32_bf16(vf[c][0], pbA0, otA[c], 0, 0, 0);
                otA[c] = __builtin_amdgcn_mfma_f32_16x16x32_bf16(vf[c][1], pbA1, otA[c], 0, 0, 0);
                otB[c] = __builtin_amdgcn_mfma_f32_16x16x32_bf16(vf[c][0], pbB0, otB[c], 0, 0, 0);
                otB[c] = __builtin_amdgcn_mfma_f32_16x16x32_bf16(vf[c][1], pbB1, otB[c], 0, 0, 0);
            }
            __builtin_amdgcn_s_setprio(0);
        }

        float lsA = lA + __shfl_xor(lA, 16);
        lsA += __shfl_xor(lsA, 32);
        float lsB = lB + __shfl_xor(lB, 16);
        lsB += __shfl_xor(lsB, 32);

        __syncthreads();
        if (h > 0) {
            float* mb = MrgF + ((size_t)(h - 1) * 64 + lane) * 36;
            mb[0] = mA; mb[1] = lsA; mb[2] = mB; mb[3] = lsB;
#pragma unroll
            for (int c = 0; c < 4; ++c)
#pragma unroll
                for (int r = 0; r < 4; ++r) {
                    mb[4 + c * 4 + r]  = otA[c][r];
                    mb[20 + c * 4 + r] = otB[c][r];
                }
        }
        __syncthreads();
        if (h == 0) {
            auto merge16 = [&](float m0, float ls0, const f32x4 (&ot)[4],
                               int mOff, int oOff, int col) {
                float mj[3], lj[3];
                float mstar = m0;
#pragma unroll
                for (int j = 0; j < 3; ++j) {
                    mj[j] = MrgF[((size_t)j * 64 + lane) * 36 + mOff];
                    lj[j] = MrgF[((size_t)j * 64 + lane) * 36 + mOff + 1];
                    mstar = fmaxf(mstar, mj[j]);
                }
                const float cs = exp2_hw(m0 - mstar);
                float cj[3];
                float den = ls0 * cs;
#pragma unroll
                for (int j = 0; j < 3; ++j) {
                    cj[j] = exp2_hw(mj[j] - mstar);
                    den += lj[j] * cj[j];
                }
                const float inv = 1.f / den;
#pragma unroll
                for (int c = 0; c < 4; ++c)
#pragma unroll
                    for (int r = 0; r < 4; ++r) {
                        float v = ot[c][r] * cs;
#pragma unroll
                        for (int j = 0; j < 3; ++j)
                            v += MrgF[((size_t)j * 64 + lane) * 36 + oOff + c * 4 + r] * cj[j];
                        v *= inv;
                        if (!finite_f(v)) v = 200.0f;   // canary
                        Olds[c * 16 + l4 * 4 + r][col] = f2b(v);
                    }
            };
            merge16(mA, lsA, otA, 0, 4, l15);
            merge16(mB, lsB, otB, 2, 20, 16 + l15);
            asm volatile("" ::: "memory");
            const int qr = lane >> 1, hf = lane & 1;
#pragma unroll
            for (int chunk = 0; chunk < 4; ++chunk) {
                u16x8 o;
#pragma unroll
                for (int j = 0; j < 8; ++j) o[j] = Olds[hf * 32 + chunk * 8 + j][qr];
                *(u16x8*)(Qp + (size_t)(qw + qr) * DD + hf * 32 + chunk * 8) = o;
            }
        }
        __syncthreads();
    }
}

// -------- proj GEMM: Y([b][h][t][d] in Q region) @ WprojT + bias -> out fp32 --------
__global__ __launch_bounds__(256) void gemm_proj(const unsigned short* __restrict__ A,
                                                 const unsigned short* __restrict__ Bt,
                                                 const void* __restrict__ bias,
                                                 float* __restrict__ outO,
                                                 const int* __restrict__ flag) {
    __shared__ unsigned short As[128 * 64];
    __shared__ unsigned short Bs[128 * 64];
    const int Ksz = CCH;
    const int tid = threadIdx.x;
    const int lane = tid & 63;
    const int wid = tid >> 6;
    const int bm = blockIdx.y * 128;
    const int bn = blockIdx.x * 128;
    const int wm = (wid >> 1) * 64;
    const int wn = (wid & 1) * 64;
    const int r8 = tid >> 3;
    const int c8 = tid & 7;
    const int cg = c8 ^ (r8 & 7);
    const int l15 = lane & 15, l4 = lane >> 4;
    const int isb = *flag;

    f32x4 acc[4][4];
#pragma unroll
    for (int i = 0; i < 4; ++i)
#pragma unroll
        for (int j = 0; j < 4; ++j)
            acc[i][j] = (f32x4){0.f, 0.f, 0.f, 0.f};

    const unsigned short* pac[4];
    const unsigned short* pbc[4];
    unsigned short* lac[4];
    unsigned short* lbc[4];
#pragma unroll
    for (int ch = 0; ch < 4; ++ch) {
        const int m = bm + ch * 32 + r8;
        pac[ch] = A + (size_t)(m >> 11) * (HH * TT * DD)
                    + (size_t)(m & 2047) * DD + cg * 8;
        pbc[ch] = Bt + (size_t)(bn + ch * 32 + r8) * Ksz + cg * 8;
        lac[ch] = &As[ch * 2048 + tid * 8];
        lbc[ch] = &Bs[ch * 2048 + tid * 8];
    }

    for (int kt = 0; kt < Ksz; kt += 64) {
        const size_t aoff = (size_t)(kt >> 6) * (TT * DD);
        __syncthreads();
#pragma unroll
        for (int ch = 0; ch < 4; ++ch) gl_lds16(pac[ch] + aoff, lac[ch]);
#pragma unroll
        for (int ch = 0; ch < 4; ++ch) gl_lds16(pbc[ch] + kt, lbc[ch]);
        __syncthreads();
#pragma unroll
        for (int kk = 0; kk < 2; ++kk) {
            short8 af[4], bfr[4];
#pragma unroll
            for (int mi = 0; mi < 4; ++mi)
                af[mi] = *(const short8*)&As[(wm + mi * 16 + l15) * 64
                                             + (((l4 + kk * 4) ^ (l15 & 7)) * 8)];
#pragma unroll
            for (int ni = 0; ni < 4; ++ni)
                bfr[ni] = *(const short8*)&Bs[(wn + ni * 16 + l15) * 64
                                              + (((l4 + kk * 4) ^ (l15 & 7)) * 8)];
#pragma unroll
            for (int mi = 0; mi < 4; ++mi)
#pragma unroll
                for (int ni = 0; ni < 4; ++ni)
                    acc[mi][ni] = __builtin_amdgcn_mfma_f32_16x16x32_bf16(
                        af[mi], bfr[ni], acc[mi][ni], 0, 0, 0);
        }
    }

#pragma unroll
    for (int mi = 0; mi < 4; ++mi) {
#pragma unroll
        for (int ni = 0; ni < 4; ++ni) {
            const int col = bn + wn + ni * 16 + l15;
            const float bv = isb ? b2f(((const unsigned short*)bias)[col])
                                 : ((const float*)bias)[col];
#pragma unroll
            for (int r = 0; r < 4; ++r) {
                const int row = bm + wm + mi * 16 + l4 * 4 + r;
                float v = acc[mi][ni][r] + bv;
                if (!finite_f(v)) v = 300.0f;   // canary
                outO[(size_t)row * CCH + col] = v;
            }
        }
    }
}

extern "C" void kernel_launch(void* const* d_in, const int* in_sizes, int n_in,
                              void* d_out, int out_size, void* d_ws, size_t ws_size,
                              hipStream_t stream) {
    const void* x     = d_in[0];
    const void* Wqkv  = d_in[1];
    const void* bqkv  = d_in[2];
    const void* Wproj = d_in[3];
    const void* bproj = d_in[4];
    float* out = (float*)d_out;

    // workspace: 58.7 MB; d_out doubles as scratch: [xb 16.78MB | Vstage 16.78MB]
    char* w = (char*)d_ws;
    int* flag = (int*)w;                          w += 256;
    unsigned short* wqkvT  = (unsigned short*)w;  w += (size_t)3 * CCH * CCH * 2;
    unsigned short* wprojT = (unsigned short*)w;  w += (size_t)CCH * CCH * 2;
    unsigned short* Qb     = (unsigned short*)w;  w += (size_t)MM * CCH * 2;
    unsigned short* Kb     = (unsigned short*)w;  w += (size_t)MM * CCH * 2;
    unsigned short* VTb    = (unsigned short*)w;  w += (size_t)MM * CCH * 2;
    unsigned short* xb     = (unsigned short*)d_out;
    unsigned short* Vstage = (unsigned short*)d_out + (size_t)MM * CCH;

    prepass_k<<<8192, 256, 0, stream>>>(x, Wqkv, Wproj, xb, wqkvT, wprojT, flag);
    gemm_qkv<<<dim3(24, 64), 256, 0, stream>>>(xb, wqkvT, bqkv, Qb, Kb, Vstage, flag);
    vtrans_k<<<dim3(32, 64), 256, 0, stream>>>(Vstage, VTb);
    attn_k<<<2048, 256, 0, stream>>>(Qb, Kb, VTb);          // writes Y over Q rows
    gemm_proj<<<dim3(8, 64), 256, 0, stream>>>(Qb, wprojT, bproj, out, flag);
}